// Round 7
// baseline (114.641 us; speedup 1.0000x reference)
//
#include <hip/hip_runtime.h>

// Fused SNN forward for MI355X (gfx950) — round 7.
// Round-6 structure, but the ENTIRE per-timestep reduction moves off the
// LDS/DS pipe onto VALU cross-lane ops:
//   xor32 exchange -> v_permlane32_swap_b32
//   xor16 butterfly -> v_permlane16_swap_b32 (both outputs summed)
//   xor8 / xor4    -> DPP row_ror:8 / row_ror:4 adds (exact xor-group sums)
// DS ops per wave per timestep: 17 -> 3 (just the predicated LDS writes).
// Also: compare m > 1.0 directly (drops the ms pre-subtract, bit-identical),
// and amdgpu_waves_per_eu(4,4) pins the allocator at the 128-VGPR budget so
// it stops rematerializing state to chase 8 waves/EU.

typedef float v2f __attribute__((ext_vector_type(2)));
typedef unsigned v2u __attribute__((ext_vector_type(2)));

#if __has_builtin(__builtin_elementwise_fma)
#define VFMA(a, b, c) __builtin_elementwise_fma((a), (b), (c))
#else
#define VFMA(a, b, c) ((a) * (b) + (c))
#endif

// x + x[lane^16]  via v_permlane16_swap (VALU pipe, no LDS traffic)
__device__ __forceinline__ float bfly16(float x) {
#if __has_builtin(__builtin_amdgcn_permlane16_swap)
    v2u r = __builtin_amdgcn_permlane16_swap(__float_as_uint(x), __float_as_uint(x),
                                             false, false);
    return __uint_as_float(r.x) + __uint_as_float(r.y);
#else
    return x + __shfl_xor(x, 16);
#endif
}

// value held by lane^32 via v_permlane32_swap
__device__ __forceinline__ float partner32(float x, bool hi) {
#if __has_builtin(__builtin_amdgcn_permlane32_swap)
    v2u r = __builtin_amdgcn_permlane32_swap(__float_as_uint(x), __float_as_uint(x),
                                             false, false);
    return __uint_as_float(hi ? r.x : r.y);
#else
    (void)hi;
    return __shfl_xor(x, 32);
#endif
}

// x + row_ror:N(x) within each 16-lane row. N=8 == xor8; N=4 (applied after
// the N=8 level, when x is period-8) == xor4.
template<int N>
__device__ __forceinline__ float dpp_ror_add(float x) {
#if __has_builtin(__builtin_amdgcn_update_dpp)
    int y = __builtin_amdgcn_update_dpp(0, __float_as_int(x), 0x120 + N, 0xf, 0xf, false);
    return x + __int_as_float(y);
#else
    return x + __shfl_xor(x, N);
#endif
}

__attribute__((amdgpu_waves_per_eu(4, 4)))
__global__ __launch_bounds__(512) void snn_fused_kernel(
    const float* __restrict__ x,       // [4096, 1, 28, 28]
    const float* __restrict__ conv_w,  // [8, 1, 3, 3]
    const float* __restrict__ fc_w,    // [10, 1352]
    float* __restrict__ out)           // [4096, 10]
{
    const int b    = blockIdx.x;
    const int tid  = threadIdx.x;
    const int lane = tid & 63;
    const int wid  = tid >> 6;

    __shared__ float sx[784];            // 28x28 image
    __shared__ float scw[72];            // conv weights
    __shared__ float sred[32 * 165];     // 32 rows x (16t*10o), stride 165
    __shared__ float scur2[160];         // [t][o]

    {
        const float4* xg  = reinterpret_cast<const float4*>(x + (size_t)b * 784);
        float4*       sx4 = reinterpret_cast<float4*>(sx);
        if (tid < 196) sx4[tid] = xg[tid];
        if (tid < 72)  scw[tid] = conv_w[tid];
    }
    __syncthreads();

    const bool hi32 = (lane & 32) != 0;
    const bool hi16 = (lane & 16) != 0;

    // ---- per-thread state (packed pairs) ----
    v2f cur2[3][2];        // conv out: [unit][{cells01, cells23}]
    v2f mem2[3][2];        // LIF-1 membranes
    v2f wl01[6], wl23[6];  // 0.25*fc_w for outputs {k0,k1},{k2,k3}
    float wl4[6];          // output k4

    #pragma unroll
    for (int i = 0; i < 3; ++i) {
        const int u      = tid + 512 * i;
        const bool valid = (u < 1352);
        const int uu  = valid ? u : 0;
        const int k   = uu / 169;
        const int rem = uu - k * 169;
        const int pr  = rem / 13;
        const int pc  = rem - pr * 13;

        float cw[9];
        #pragma unroll
        for (int q = 0; q < 9; ++q) cw[q] = scw[k * 9 + q];

        float xr[4][4];
        #pragma unroll
        for (int r = 0; r < 4; ++r) {
            const float2* row = reinterpret_cast<const float2*>(&sx[(2 * pr + r) * 28 + 2 * pc]);
            const float2 a = row[0], c2 = row[1];
            xr[r][0] = a.x; xr[r][1] = a.y; xr[r][2] = c2.x; xr[r][3] = c2.y;
        }

        float cell[2][2];
        #pragma unroll
        for (int dr = 0; dr < 2; ++dr)
            #pragma unroll
            for (int dc = 0; dc < 2; ++dc) {
                float acc = 0.0f;
                #pragma unroll
                for (int ki = 0; ki < 3; ++ki)
                    #pragma unroll
                    for (int kj = 0; kj < 3; ++kj)
                        acc += xr[dr + ki][dc + kj] * cw[ki * 3 + kj];
                cell[dr][dc] = valid ? acc : 0.0f;
            }
        cur2[i][0] = (v2f){cell[0][0], cell[0][1]};
        cur2[i][1] = (v2f){cell[1][0], cell[1][1]};
        mem2[i][0] = (v2f){0.0f, 0.0f};
        mem2[i][1] = (v2f){0.0f, 0.0f};
    }

    // weights: own units (j=0..2) and lane^32-partner units (j=3..5)
    #pragma unroll
    for (int j = 0; j < 6; ++j) {
        const int bt     = (j < 3) ? tid : (tid ^ 32);
        const int u      = bt + 512 * (j % 3);
        const bool valid = (u < 1352);
        const int uu     = valid ? u : 0;
        const int ob     = hi32 ? 5 : 0;
        const float sc   = valid ? 0.25f : 0.0f;
        wl01[j] = (v2f){sc * fc_w[(ob + 0) * 1352 + uu], sc * fc_w[(ob + 1) * 1352 + uu]};
        wl23[j] = (v2f){sc * fc_w[(ob + 2) * 1352 + uu], sc * fc_w[(ob + 3) * 1352 + uu]};
        wl4[j]  = sc * fc_w[(ob + 4) * 1352 + uu];
    }

    const v2f half2 = (v2f){0.5f, 0.5f};

    // stageA: one LIF step on own units (packed) + permlane count exchange + FC
    auto stageA = [&](v2f& nv01, v2f& nv23, float& nv4) {
        float c[3];
        #pragma unroll
        for (int i = 0; i < 3; ++i) {
            v2f m01 = VFMA(half2, mem2[i][0], cur2[i][0]);
            v2f m23 = VFMA(half2, mem2[i][1], cur2[i][1]);
            v2f sp01, sp23;
            sp01.x = m01.x > 1.0f ? 1.0f : 0.0f;   // spike iff m > THR
            sp01.y = m01.y > 1.0f ? 1.0f : 0.0f;
            sp23.x = m23.x > 1.0f ? 1.0f : 0.0f;
            sp23.y = m23.y > 1.0f ? 1.0f : 0.0f;
            mem2[i][0] = m01 - sp01;               // subtract-reset (bit-identical)
            mem2[i][1] = m23 - sp23;
            v2f s = sp01 + sp23;
            c[i] = s.x + s.y;                      // 0..4 exact
        }
        float p[3];
        p[0] = partner32(c[0], hi32);
        p[1] = partner32(c[1], hi32);
        p[2] = partner32(c[2], hi32);

        nv01 = (v2f){0.0f, 0.0f};
        nv23 = (v2f){0.0f, 0.0f};
        nv4  = 0.0f;
        #pragma unroll
        for (int i = 0; i < 3; ++i) {              // own units
            const v2f f2 = (v2f){c[i], c[i]};
            nv01 = VFMA(wl01[i], f2, nv01);
            nv23 = VFMA(wl23[i], f2, nv23);
            nv4  = __builtin_fmaf(wl4[i], c[i], nv4);
        }
        #pragma unroll
        for (int i = 0; i < 3; ++i) {              // partner units
            const v2f f2 = (v2f){p[i], p[i]};
            nv01 = VFMA(wl01[3 + i], f2, nv01);
            nv23 = VFMA(wl23[3 + i], f2, nv23);
            nv4  = __builtin_fmaf(wl4[3 + i], p[i], nv4);
        }
    };

    v2f v01, v23; float v4;
    stageA(v01, v23, v4);                          // t = 0 partials

    const int q   = lane >> 4;                     // quadrant 0..3
    const int bo  = (q & 1) * 2 + (q >> 1) * 5;    // {0,2,5,7}
    const int to  = 4 + (q >> 1) * 5;              // {4,4,9,9}
    const int row = wid * 4 + (lane & 3);          // 32 rows total

    #pragma unroll
    for (int t = 0; t < 16; ++t) {
        // xor16 butterfly sums (VALU permlane, no DS)
        const float a0 = bfly16(v01.x);
        const float a1 = bfly16(v01.y);
        const float a2 = bfly16(v23.x);
        const float a3 = bfly16(v23.y);
        const float a4 = bfly16(v4);

        v2f nv01, nv23; float nv4;
        if (t < 15) {
            stageA(nv01, nv23, nv4);
        } else {
            nv01 = (v2f){0.0f, 0.0f};
            nv23 = (v2f){0.0f, 0.0f};
            nv4  = 0.0f;
        }

        // fold 5 -> 3, then xor8 / xor4 via DPP row_ror adds
        float w0 = hi16 ? a2 : a0;
        float w1 = hi16 ? a3 : a1;
        float w2 = a4;
        w0 = dpp_ror_add<8>(w0);
        w1 = dpp_ror_add<8>(w1);
        w2 = dpp_ror_add<8>(w2);
        w0 = dpp_ror_add<4>(w0);
        w1 = dpp_ror_add<4>(w1);
        w2 = dpp_ror_add<4>(w2);

        // 4 rows per wave; duplicate equal-value writes of w2 are benign
        if ((lane & 12) == 0) {
            const int base = row * 165 + t * 10;
            sred[base + bo]     = w0;
            sred[base + bo + 1] = w1;
            sred[base + to]     = w2;
        }

        v01 = nv01; v23 = nv23; v4 = nv4;
    }
    __syncthreads();

    // ---- final reduce: 160 threads, one (t,o) each, 32 rows ----
    if (tid < 160) {
        float sum = 0.0f;
        #pragma unroll
        for (int r = 0; r < 32; ++r)
            sum += sred[r * 165 + tid];
        scur2[tid] = sum;
    }
    __syncthreads();

    // ---- LIF-2 scan, 10 lanes ----
    if (tid < 10) {
        float m2 = 0.0f, cnt = 0.0f;
        #pragma unroll
        for (int t = 0; t < 16; ++t) {
            m2 = __builtin_fmaf(0.5f, m2, scur2[t * 10 + tid]);
            float ms = m2 - 1.0f;
            bool  sp = ms > 0.0f;
            m2  = sp ? ms : m2;
            cnt += sp ? 1.0f : 0.0f;
        }
        out[(size_t)b * 10 + tid] = cnt;
    }
}

extern "C" void kernel_launch(void* const* d_in, const int* in_sizes, int n_in,
                              void* d_out, int out_size, void* d_ws, size_t ws_size,
                              hipStream_t stream) {
    const float* x      = (const float*)d_in[0];  // 4096*784
    const float* conv_w = (const float*)d_in[1];  // 72
    const float* fc_w   = (const float*)d_in[2];  // 13520
    float* out          = (float*)d_out;          // 40960

    const int B = in_sizes[0] / 784;              // 4096
    snn_fused_kernel<<<B, 512, 0, stream>>>(x, conv_w, fc_w, out);
}